// Round 9
// baseline (137.936 us; speedup 1.0000x reference)
//
#include <hip/hip_runtime.h>

#define NUM_EMB 1024
#define EMB_DIM 256
#define MARGIN 1e-3f

typedef __attribute__((ext_vector_type(8))) short short8v;
typedef __attribute__((ext_vector_type(4))) float f32x4;
typedef unsigned long long u64;
typedef unsigned int u32;

__device__ __forceinline__ u32 sortable(float f) {
    u32 u = __float_as_uint(f);
    return (u & 0x80000000u) ? ~u : (u | 0x80000000u);
}
__device__ __forceinline__ float unsortable(u32 s) {
    u32 u = (s & 0x80000000u) ? (s & 0x7FFFFFFFu) : ~s;
    return __uint_as_float(u);
}
__device__ __forceinline__ u64 umin64(u64 a, u64 b) { return a < b ? a : b; }

// RNE fp32 -> bf16 bits
__device__ __forceinline__ unsigned short f2bf(float f) {
    u32 u = __float_as_uint(f);
    u32 r = (u + 0x7FFFu + ((u >> 16) & 1u)) >> 16;
    return (unsigned short)r;
}
__device__ __forceinline__ float bf2f(unsigned short h) {
    return __uint_as_float(((u32)h) << 16);
}

#define GLP(p)  ((const __attribute__((address_space(1))) unsigned int*)(p))
#define LDSP(p) ((__attribute__((address_space(3))) unsigned int*)(p))

// ---- fused prep: role-split by blockIdx (r4/r7-proven logic) ----
__global__ __launch_bounds__(512)
void vq_prep(const float* __restrict__ X, const float* __restrict__ E,
             float* __restrict__ ET, float* __restrict__ normE,
             char* __restrict__ Es, char* __restrict__ Xs) {
    __shared__ float tile[64][65];
    const int bid = blockIdx.x;
    const int t = threadIdx.x;
    if (bid < 64) {
        const int j0 = (bid & 15) * 64, d0 = (bid >> 4) * 64;
        const int tj = t & 63, td = t >> 6;
#pragma unroll
        for (int k = 0; k < 8; k++) {
            int dl = k * 8 + td;
            tile[dl][tj] = E[(d0 + dl) * NUM_EMB + j0 + tj];
        }
        __syncthreads();
        const int dd = t & 63, tw = t >> 6;
#pragma unroll
        for (int k = 0; k < 8; k++) {
            int jj = k * 8 + tw;
            ET[(j0 + jj) * EMB_DIM + d0 + dd] = tile[dd][jj];
        }
    } else if (bid < 66) {
        const int j = (bid - 64) * 512 + t;
        float s = 0.f;
#pragma unroll 8
        for (int d = 0; d < EMB_DIM; d++) {
            float v = E[d * NUM_EMB + j];
            s = fmaf(v, v, s);
        }
        normE[j] = s;
    } else if (bid < 98) {
        const int rb = bid - 66;                // 0..31
        const int nblk = rb >> 3, ks = rb & 7;
#pragma unroll
        for (int i = 0; i < 4; i++) {
            int gid = i * 512 + t;              // 256 cols x 8 k8-groups
            int col = gid >> 3;
            int k8 = gid & 7;
            int kg = ks * 64 + k8 * 8;
            int isLo = kg >= 256;
            int d0 = isLo ? kg - 256 : kg;
            int colg = nblk * 256 + col;
            short8v v;
#pragma unroll
            for (int j = 0; j < 8; j++) {
                float e = E[(d0 + j) * NUM_EMB + colg];
                unsigned short h = f2bf(e);
                if (isLo) h = f2bf(e - bf2f(h));
                v[j] = (short)h;
            }
            size_t off = (size_t)nblk * 262144 + (size_t)ks * 32768 +
                         (size_t)(((col * 128 + (k8 * 8) * 2) ^ ((col & 7) << 4)));
            *(short8v*)(Es + off) = v;
        }
    } else {
        const int mblk = bid - 98;              // 0..255
#pragma unroll
        for (int i = 0; i < 8; i++) {
            int gid = i * 512 + t;              // 128 rows x 32 d8-groups
            int row = gid >> 5;
            int d0 = (gid & 31) * 8;
            const float4* xp4 = (const float4*)(X + ((size_t)mblk * 128 + row) * 256 + d0);
            float4 xa = xp4[0], xb = xp4[1];
            float xv[8] = {xa.x, xa.y, xa.z, xa.w, xb.x, xb.y, xb.z, xb.w};
            short8v vh, vl;
#pragma unroll
            for (int j = 0; j < 8; j++) {
                unsigned short h = f2bf(xv[j]);
                vh[j] = (short)h;
                vl[j] = (short)f2bf(xv[j] - bf2f(h));
            }
            int ksh = d0 >> 6, kl = d0 & 63;
            size_t inner = (size_t)(((row * 128 + kl * 2) ^ ((row & 7) << 4)));
            size_t base = (size_t)mblk * 131072;
            *(short8v*)(Xs + base + (size_t)ksh * 16384 + inner) = vh;
            *(short8v*)(Xs + base + (size_t)(ksh + 4) * 16384 + inner) = vl;
        }
    }
}

// ---- GEMM + per-block argmin/second-best ----
// r7-proven geometry: grid 1024 = 256 mblk x 4 nblk (XCD-swizzled); 512 thr;
// BM=128 BN=256 BK=64; dbuf LDS 96KB (A 16K + B 32K per buf).
// NEW (r9): 2-phase interleave + 2-deep staging + setprio.
//   step s: PhaseA {ds_read F_B(s) || 16 MFMA F_A(s)}; lgkm(0); bar1;
//           STAGE(s+2) -> buf s&1 (reads drained); vmcnt(6) (s+1 landed); bar2;
//           PhaseB {ds_read F_A(s+1) from buf (s+1)&1 || 16 MFMA F_B(s)}.
// K=768 schedule: D = Xh*Eh + Xh*El + Xl*Eh
__global__ __launch_bounds__(512, 1)
void vq_gemm(const char* __restrict__ Xs, const char* __restrict__ Es,
             const float* __restrict__ normE,
             u64* __restrict__ gkey, float* __restrict__ gm2) {
    extern __shared__ char smem[];
    const int t = threadIdx.x;
    const int bid = blockIdx.x;
    const int lbid = (bid & 7) * 128 + (bid >> 3);
    const int mblk = lbid >> 2;
    const int nblk = lbid & 3;
    const int w = t >> 6, l = t & 63;
    const int wm = w >> 2, wn = w & 3;
    const int lr = l & 15, lg = l >> 4;
    const int swz = (l & 7) << 4;

    const char* Asrc = Xs + (size_t)mblk * 131072;
    const char* Bsrc = Es + (size_t)nblk * 262144;

    // LDS frag bases (buf-relative)
    const int aB0 = (wm * 64 + lr) * 128 + ((lg * 16) ^ swz);
    const int aB1 = (wm * 64 + lr) * 128 + ((64 + lg * 16) ^ swz);
    const int bB0 = 16384 + (wn * 64 + lr) * 128 + ((lg * 16) ^ swz);
    const int bB1 = 16384 + (wn * 64 + lr) * 128 + ((64 + lg * 16) ^ swz);

    f32x4 acc[4][4];
#pragma unroll
    for (int mt = 0; mt < 4; mt++)
#pragma unroll
        for (int nt = 0; nt < 4; nt++) acc[mt][nt] = (f32x4){0.f, 0.f, 0.f, 0.f};

#define STAGE(aks, bks, buf) {                                                    \
    const char* as_ = Asrc + (aks) * 16384;                                       \
    const char* bs_ = Bsrc + (bks) * 32768;                                       \
    char* ab_ = smem + (buf) * 49152;                                             \
    char* bb_ = ab_ + 16384;                                                      \
    __builtin_amdgcn_global_load_lds(GLP(as_ + t * 16),        LDSP(ab_ + t * 16), 16, 0, 0);        \
    __builtin_amdgcn_global_load_lds(GLP(as_ + 8192 + t * 16), LDSP(ab_ + 8192 + t * 16), 16, 0, 0); \
    __builtin_amdgcn_global_load_lds(GLP(bs_ + t * 16),         LDSP(bb_ + t * 16), 16, 0, 0);        \
    __builtin_amdgcn_global_load_lds(GLP(bs_ + 8192 + t * 16),  LDSP(bb_ + 8192 + t * 16), 16, 0, 0); \
    __builtin_amdgcn_global_load_lds(GLP(bs_ + 16384 + t * 16), LDSP(bb_ + 16384 + t * 16), 16, 0, 0);\
    __builtin_amdgcn_global_load_lds(GLP(bs_ + 24576 + t * 16), LDSP(bb_ + 24576 + t * 16), 16, 0, 0);\
}

    short8v faa[4], fab[4], fba[4], fbb[4];

    // prologue: tile0 resident; issue tile1; preload F_A(0)
    STAGE(0, 0, 0);
    asm volatile("s_waitcnt vmcnt(0)" ::: "memory");
    __builtin_amdgcn_s_barrier();
    asm volatile("" ::: "memory");
    STAGE(1, 1, 1);
#pragma unroll
    for (int mt = 0; mt < 4; mt++) faa[mt] = *(const short8v*)(smem + aB0 + mt * 2048);
#pragma unroll
    for (int nt = 0; nt < 4; nt++) fab[nt] = *(const short8v*)(smem + bB0 + nt * 2048);

#pragma unroll
    for (int s = 0; s < 12; s++) {
        const char* cb = smem + (s & 1) * 49152;
        // ---- Phase A: prefetch F_B(s), compute F_A(s)
#pragma unroll
        for (int mt = 0; mt < 4; mt++) fba[mt] = *(const short8v*)(cb + aB1 + mt * 2048);
#pragma unroll
        for (int nt = 0; nt < 4; nt++) fbb[nt] = *(const short8v*)(cb + bB1 + nt * 2048);
        __builtin_amdgcn_s_setprio(1);
#pragma unroll
        for (int mt = 0; mt < 4; mt++)
#pragma unroll
            for (int nt = 0; nt < 4; nt++)
                acc[mt][nt] = __builtin_amdgcn_mfma_f32_16x16x32_bf16(faa[mt], fab[nt], acc[mt][nt], 0, 0, 0);
        __builtin_amdgcn_s_setprio(0);
        asm volatile("s_waitcnt lgkmcnt(0)" ::: "memory");
        __builtin_amdgcn_sched_barrier(0);
        __builtin_amdgcn_s_barrier();          // bar1: all F_B reads of buf s&1 done
        asm volatile("" ::: "memory");
        if (s < 10) {
            const int s2 = s + 2;
            const int an2 = (s2 < 8) ? (s2 & 3) : (s2 - 4);
            const int bn2 = (s2 < 8) ? s2 : (s2 - 8);
            STAGE(an2, bn2, s & 1);            // overwrite drained buf
            asm volatile("s_waitcnt vmcnt(6)" ::: "memory");   // STAGE(s+1) landed
        } else if (s == 10) {
            asm volatile("s_waitcnt vmcnt(0)" ::: "memory");   // STAGE(11) landed
        }
        if (s < 11) {
            __builtin_amdgcn_s_barrier();      // bar2: tile s+1 visible to all
            asm volatile("" ::: "memory");
            const char* nb = smem + ((s + 1) & 1) * 49152;
#pragma unroll
            for (int mt = 0; mt < 4; mt++) faa[mt] = *(const short8v*)(nb + aB0 + mt * 2048);
#pragma unroll
            for (int nt = 0; nt < 4; nt++) fab[nt] = *(const short8v*)(nb + bB0 + nt * 2048);
        }
        // ---- Phase B: compute F_B(s) (F_A(s+1) loads in flight above)
        __builtin_amdgcn_s_setprio(1);
#pragma unroll
        for (int mt = 0; mt < 4; mt++)
#pragma unroll
            for (int nt = 0; nt < 4; nt++)
                acc[mt][nt] = __builtin_amdgcn_mfma_f32_16x16x32_bf16(fba[mt], fbb[nt], acc[mt][nt], 0, 0, 0);
        __builtin_amdgcn_s_setprio(0);
    }
#undef STAGE

    // epilogue: per-lane argmin over nt, then 16-lane reduce; track second-best
    float ne_v[4];
#pragma unroll
    for (int nt = 0; nt < 4; nt++) ne_v[nt] = normE[nblk * 256 + wn * 64 + nt * 16 + lr];

#pragma unroll
    for (int mt = 0; mt < 4; mt++) {
#pragma unroll
        for (int r = 0; r < 4; r++) {
            float m1 = __uint_as_float(0x7F7FFFFFu);   // FLT_MAX
            float m2 = m1;
            u32 col = 0;
#pragma unroll
            for (int nt = 0; nt < 4; nt++) {
                float f = fmaf(-2.0f, acc[mt][nt][r], ne_v[nt]);
                float mx = fmaxf(m1, f);
                m2 = fminf(m2, mx);
                bool p = f < m1;
                m1 = fminf(m1, f);
                u32 cg = (u32)(nblk * 256 + wn * 64 + nt * 16 + lr);
                col = p ? cg : col;
            }
            u64 key = ((u64)sortable(m1) << 32) | col;
#pragma unroll
            for (int off = 1; off < 16; off <<= 1) {
                u64 ko = __shfl_xor(key, off, 16);
                float m1o = __shfl_xor(m1, off, 16);
                float m2o = __shfl_xor(m2, off, 16);
                m2 = fminf(fminf(m2, m2o), fmaxf(m1, m1o));
                m1 = fminf(m1, m1o);
                key = umin64(key, ko);
            }
            if (lr == 0) {
                int slot = (wm * 64 + mt * 16 + lg * 4 + r) * 4 + wn;
                *(u64*)(smem + slot * 16) = key;
                *(float*)(smem + slot * 16 + 8) = m2;
            }
        }
    }
    __syncthreads();
    if (t < 128) {
        u64 k_i[4]; float m2_i[4];
#pragma unroll
        for (int i = 0; i < 4; i++) {
            k_i[i] = *(const u64*)(smem + (t * 4 + i) * 16);
            m2_i[i] = *(const float*)(smem + (t * 4 + i) * 16 + 8);
        }
        u64 K = umin64(umin64(k_i[0], k_i[1]), umin64(k_i[2], k_i[3]));
        float F2 = __uint_as_float(0x7F7FFFFFu);
#pragma unroll
        for (int i = 0; i < 4; i++) {
            float f1i = unsortable((u32)(k_i[i] >> 32));
            F2 = fminf(F2, (k_i[i] == K) ? m2_i[i] : f1i);
        }
        int rowg = mblk * 128 + t;
        gkey[(size_t)nblk * 32768 + rowg] = K;
        gm2[(size_t)nblk * 32768 + rowg] = F2;
    }
}

// ---- combine 4 nblk results -> idx + flag list ----
__global__ __launch_bounds__(512) void vq_combine(const u64* __restrict__ gkey, const float* __restrict__ gm2,
                                                  u32* __restrict__ idx_arr, u32* __restrict__ flaglist,
                                                  u32* __restrict__ cnt) {
    const int row = blockIdx.x * 512 + threadIdx.x;
    u64 k_i[4]; float m2_i[4];
#pragma unroll
    for (int n = 0; n < 4; n++) {
        k_i[n] = gkey[(size_t)n * 32768 + row];
        m2_i[n] = gm2[(size_t)n * 32768 + row];
    }
    u64 K = umin64(umin64(k_i[0], k_i[1]), umin64(k_i[2], k_i[3]));
    float F1 = unsortable((u32)(K >> 32));
    float F2 = __uint_as_float(0x7F7FFFFFu);
#pragma unroll
    for (int n = 0; n < 4; n++) {
        float f1i = unsortable((u32)(k_i[n] >> 32));
        F2 = fminf(F2, (k_i[n] == K) ? m2_i[n] : f1i);
    }
    idx_arr[row] = (u32)(K & 0xFFFFFFFFu);
    if (F2 - F1 < MARGIN) {
        u32 p = atomicAdd(cnt, 1u);
        flaglist[p] = (u32)row;
    }
}

// ---- exact fp32 recheck of flagged rows (bit-identical to verified round-2 math) ----
__global__ __launch_bounds__(512) void vq_recheck(const float* __restrict__ X, const float* __restrict__ E,
                                                  const float* __restrict__ normE,
                                                  const u32* __restrict__ flaglist, const u32* __restrict__ cnt,
                                                  u32* __restrict__ idx_arr) {
    __shared__ float xrow[256];
    __shared__ float r2part[32];
    __shared__ float r2s;
    __shared__ u64 wkey[8];
    const int t = threadIdx.x;
    const int n = (int)*cnt;
    for (int i = blockIdx.x; i < n; i += 256) {
        const int row = (int)flaglist[i];
        __syncthreads();
        if (t < 64) ((float4*)xrow)[t] = ((const float4*)(X + (size_t)row * 256))[t];
        __syncthreads();
        if (t < 32) {
            float s = 0.f;
#pragma unroll
            for (int k = 0; k < 8; k++) {
                float v = xrow[t * 8 + k];
                s = fmaf(v, v, s);
            }
            r2part[t] = s;
        }
        __syncthreads();
        if (t == 0) {
            float s = 0.f;
#pragma unroll
            for (int k = 0; k < 32; k++) s += r2part[k];
            r2s = s;
        }
        __syncthreads();
        const float r2 = r2s;
        const int c0 = t * 2;
        float ax = 0.f, ay = 0.f;
        for (int d = 0; d < 256; d += 4) {
#pragma unroll
            for (int dd = 0; dd < 4; dd++) {
                float xv = xrow[d + dd];
                float2 e = *(const float2*)(E + (d + dd) * NUM_EMB + c0);
                ax = fmaf(xv, e.x, ax);
                ay = fmaf(xv, e.y, ay);
            }
        }
        float2 ne = *(const float2*)(normE + c0);
        float f0 = (r2 + ne.x) - 2.0f * ax;
        float f1 = (r2 + ne.y) - 2.0f * ay;
        u64 k0 = ((u64)sortable(f0) << 32) | (u32)c0;
        u64 k1 = ((u64)sortable(f1) << 32) | (u32)(c0 + 1);
        u64 km = umin64(k0, k1);
#pragma unroll
        for (int off = 32; off; off >>= 1) km = umin64(km, __shfl_xor(km, off, 64));
        if ((t & 63) == 0) wkey[t >> 6] = km;
        __syncthreads();
        if (t == 0) {
            u64 m = wkey[0];
#pragma unroll
            for (int w2 = 1; w2 < 8; w2++) m = umin64(m, wkey[w2]);
            idx_arr[row] = (u32)(m & 0xFFFFFFFFull);
        }
    }
}

// ---- straight-through out + loss partials ----
__global__ __launch_bounds__(512) void vq_out(const float* __restrict__ X, const float* __restrict__ ET,
                                              const u32* __restrict__ idx_arr,
                                              float* __restrict__ out, float* __restrict__ partial) {
    __shared__ float lred[8];
    const int t = threadIdx.x;
    const long long base = (long long)blockIdx.x * 4096;   // 16 rows * 256
    const int dcol = t & 255, half = t >> 8;
    float lsum = 0.f;
#pragma unroll
    for (int rr = 0; rr < 8; rr++) {
        const int r = half * 8 + rr;
        const int row = blockIdx.x * 16 + r;
        const u32 idx = idx_arr[row];
        const float q = ET[(size_t)idx * EMB_DIM + dcol];
        const float x = X[base + r * EMB_DIM + dcol];
        out[base + r * EMB_DIM + dcol] = x + (q - x);
        const float df = x - q;
        lsum = fmaf(df, df, lsum);
    }
#pragma unroll
    for (int off = 32; off; off >>= 1) lsum += __shfl_down(lsum, off, 64);
    if ((t & 63) == 0) lred[t >> 6] = lsum;
    __syncthreads();
    if (t == 0) {
        float s = 0.f;
#pragma unroll
        for (int w = 0; w < 8; w++) s += lred[w];
        partial[blockIdx.x] = s;
    }
}

// ---- finish: loss = m + 0.25*m ----
__global__ void vq_finish(const float* __restrict__ partial, float* __restrict__ loss_out) {
    __shared__ float red[256];
    const int t = threadIdx.x;
    float s = 0.f;
    for (int i = t; i < 2048; i += 256) s += partial[i];
    red[t] = s;
    __syncthreads();
    for (int k = 128; k > 0; k >>= 1) {
        if (t < k) red[t] += red[t + k];
        __syncthreads();
    }
    if (t == 0) {
        const float m = red[0] / 8388608.0f;
        loss_out[0] = fmaf(0.25f, m, m);
    }
}

extern "C" void kernel_launch(void* const* d_in, const int* in_sizes, int n_in,
                              void* d_out, int out_size, void* d_ws, size_t ws_size,
                              hipStream_t stream) {
    const float* X = (const float*)d_in[0];      // (32,32,32,256) fp32
    const float* E = (const float*)d_in[1];      // (256,1024) fp32
    float* out = (float*)d_out;

    // workspace layout (bytes)
    char* ws = (char*)d_ws;
    float* ET       = (float*)(ws + 0);            // 1 MB
    float* normE    = (float*)(ws + 1048576);      // 4 KB
    float* partial  = (float*)(ws + 1052672);      // 8 KB
    char*  Es       = ws + 1060864;                // 1 MB
    u64*   gkey     = (u64*)(ws + 2109440);        // 1 MB
    float* gm2      = (float*)(ws + 3158016);      // 512 KB
    u32*   idx_arr  = (u32*)(ws + 3682304);        // 128 KB
    u32*   flaglist = (u32*)(ws + 3813376);        // 128 KB
    u32*   cnt      = (u32*)(ws + 3944448);        // 4 B

    // Xs (bf16 hi/lo, 32 MB) aliases d_out; fully consumed before vq_out overwrites.
    char* Xs = (char*)d_out;

    hipMemsetAsync(cnt, 0, 4, stream);
    vq_prep<<<354, 512, 0, stream>>>(X, E, ET, normE, Es, Xs);
    vq_gemm<<<1024, 512, 98304, stream>>>(Xs, Es, normE, gkey, gm2);
    vq_combine<<<64, 512, 0, stream>>>(gkey, gm2, idx_arr, flaglist, cnt);
    vq_recheck<<<256, 512, 0, stream>>>(X, E, normE, flaglist, cnt, idx_arr);
    vq_out<<<2048, 512, 0, stream>>>(X, ET, idx_arr, out, partial);
    vq_finish<<<1, 256, 0, stream>>>(partial, out + (out_size - 1));
}

// Round 10
// 129.675 us; speedup vs baseline: 1.0637x; 1.0637x over previous
//
#include <hip/hip_runtime.h>

#define NUM_EMB 1024
#define EMB_DIM 256
#define MARGIN 1e-3f

typedef __attribute__((ext_vector_type(8))) short short8v;
typedef __attribute__((ext_vector_type(4))) float f32x4;
typedef unsigned long long u64;
typedef unsigned int u32;

__device__ __forceinline__ u32 sortable(float f) {
    u32 u = __float_as_uint(f);
    return (u & 0x80000000u) ? ~u : (u | 0x80000000u);
}
__device__ __forceinline__ float unsortable(u32 s) {
    u32 u = (s & 0x80000000u) ? (s & 0x7FFFFFFFu) : ~s;
    return __uint_as_float(u);
}
__device__ __forceinline__ u64 umin64(u64 a, u64 b) { return a < b ? a : b; }

// RNE fp32 -> bf16 bits
__device__ __forceinline__ unsigned short f2bf(float f) {
    u32 u = __float_as_uint(f);
    u32 r = (u + 0x7FFFu + ((u >> 16) & 1u)) >> 16;
    return (unsigned short)r;
}
__device__ __forceinline__ float bf2f(unsigned short h) {
    return __uint_as_float(((u32)h) << 16);
}

#define GLP(p)  ((const __attribute__((address_space(1))) unsigned int*)(p))
#define LDSP(p) ((__attribute__((address_space(3))) unsigned int*)(p))

// ---- fused prep: role-split by blockIdx ----
// bid 0..63   : transpose E -> ET;  64..65: normE;  66..97: eprep (unchanged)
// bid 98..353 : xprep -> Xs as [mblk128 of 256 rows][kstep 0..7][32KB tile]
//               tile byte = (row*128 + kl*2) ^ ((row&7)<<4); ks 0-3 hi, 4-7 lo
__global__ __launch_bounds__(512)
void vq_prep(const float* __restrict__ X, const float* __restrict__ E,
             float* __restrict__ ET, float* __restrict__ normE,
             char* __restrict__ Es, char* __restrict__ Xs) {
    __shared__ float tile[64][65];
    const int bid = blockIdx.x;
    const int t = threadIdx.x;
    if (bid < 64) {
        const int j0 = (bid & 15) * 64, d0 = (bid >> 4) * 64;
        const int tj = t & 63, td = t >> 6;
#pragma unroll
        for (int k = 0; k < 8; k++) {
            int dl = k * 8 + td;
            tile[dl][tj] = E[(d0 + dl) * NUM_EMB + j0 + tj];
        }
        __syncthreads();
        const int dd = t & 63, tw = t >> 6;
#pragma unroll
        for (int k = 0; k < 8; k++) {
            int jj = k * 8 + tw;
            ET[(j0 + jj) * EMB_DIM + d0 + dd] = tile[dd][jj];
        }
    } else if (bid < 66) {
        const int j = (bid - 64) * 512 + t;
        float s = 0.f;
#pragma unroll 8
        for (int d = 0; d < EMB_DIM; d++) {
            float v = E[d * NUM_EMB + j];
            s = fmaf(v, v, s);
        }
        normE[j] = s;
    } else if (bid < 98) {
        const int rb = bid - 66;                // 0..31
        const int nblk = rb >> 3, ks = rb & 7;
#pragma unroll
        for (int i = 0; i < 4; i++) {
            int gid = i * 512 + t;              // 256 cols x 8 k8-groups
            int col = gid >> 3;
            int k8 = gid & 7;
            int kg = ks * 64 + k8 * 8;
            int isLo = kg >= 256;
            int d0 = isLo ? kg - 256 : kg;
            int colg = nblk * 256 + col;
            short8v v;
#pragma unroll
            for (int j = 0; j < 8; j++) {
                float e = E[(d0 + j) * NUM_EMB + colg];
                unsigned short h = f2bf(e);
                if (isLo) h = f2bf(e - bf2f(h));
                v[j] = (short)h;
            }
            size_t off = (size_t)nblk * 262144 + (size_t)ks * 32768 +
                         (size_t)(((col * 128 + (k8 * 8) * 2) ^ ((col & 7) << 4)));
            *(short8v*)(Es + off) = v;
        }
    } else {
        const int pb = bid - 98;                // 0..255
        const int mblk = pb >> 1;               // 0..127 (256-row tiles)
        const int rhalf = (pb & 1) * 128;
#pragma unroll
        for (int i = 0; i < 8; i++) {
            int gid = i * 512 + t;              // 128 rows x 32 d8-groups
            int row = rhalf + (gid >> 5);       // 0..255
            int d0 = (gid & 31) * 8;
            const float4* xp4 = (const float4*)(X + ((size_t)mblk * 256 + row) * 256 + d0);
            float4 xa = xp4[0], xb = xp4[1];
            float xv[8] = {xa.x, xa.y, xa.z, xa.w, xb.x, xb.y, xb.z, xb.w};
            short8v vh, vl;
#pragma unroll
            for (int j = 0; j < 8; j++) {
                unsigned short h = f2bf(xv[j]);
                vh[j] = (short)h;
                vl[j] = (short)f2bf(xv[j] - bf2f(h));
            }
            int ksh = d0 >> 6, kl = d0 & 63;
            size_t inner = (size_t)(((row * 128 + kl * 2) ^ ((row & 7) << 4)));
            size_t base = (size_t)mblk * 262144;
            *(short8v*)(Xs + base + (size_t)ksh * 32768 + inner) = vh;
            *(short8v*)(Xs + base + (size_t)(ksh + 4) * 32768 + inner) = vl;
        }
    }
}

// ---- GEMM + per-block argmin/second-best: 8-phase template port ----
// grid 512 = 128 mblk x 4 nblk (XCD swizzle); 512 thr (8 waves 2x4, wave tile 128x64)
// BM=256 BN=256 BK=64; LDS 128KB = 2 bufs x (A 32K + B 32K)
// 12 K-steps; per step 4 phases: (kk, mt-half) = (0,lo),(0,hi),(1,lo),(1,hi)
//   each phase: ds_read (4 A [+4 B on kk entry]) ; 2 global_load_lds ; barrier ;
//               lgkmcnt(0)+sched_barrier ; setprio(1) ; 16 MFMA ; setprio(0) ; barrier
// staging: tile s+1 (8 loads) spread 2/phase; vmcnt(0) once at step boundary
// K=768: A ksteps {0,1,2,3,0,1,2,3,4,5,6,7}; B ksteps {0,1,2,3,4,5,6,7,0,1,2,3}
__global__ __launch_bounds__(512, 1)
void vq_gemm(const char* __restrict__ Xs, const char* __restrict__ Es,
             const float* __restrict__ normE,
             u64* __restrict__ gkey, float* __restrict__ gm2) {
    extern __shared__ char smem[];
    const int t = threadIdx.x;
    const int bid = blockIdx.x;
    const int lbid = (bid & 7) * 64 + (bid >> 3);   // bijective, 512 = 8 XCD x 64
    const int mblk = lbid >> 2;
    const int nblk = lbid & 3;
    const int w = t >> 6, l = t & 63;
    const int wm = w >> 2, wn = w & 3;              // 2 x 4 wave grid
    const int lr = l & 15, lg = l >> 4;
    const int swz = (l & 7) << 4;

    const char* Asrc = Xs + (size_t)mblk * 262144;
    const char* Bsrc = Es + (size_t)nblk * 262144;

    const int aBase = (wm * 128 + lr) * 128;        // + mt*2048 + coff
    const int bBase = (wn * 64 + lr) * 128;         // + nt*2048 + coff (within B region)
    const int c0off = (lg * 16) ^ swz;
    const int c1off = (64 + lg * 16) ^ swz;

    f32x4 acc[8][4];
#pragma unroll
    for (int mt = 0; mt < 8; mt++)
#pragma unroll
        for (int nt = 0; nt < 4; nt++) acc[mt][nt] = (f32x4){0.f, 0.f, 0.f, 0.f};

#define GLL(srcp, dstoff) __builtin_amdgcn_global_load_lds(GLP(srcp), LDSP(smem + (dstoff)), 16, 0, 0)
#define BARRIER() { asm volatile("" ::: "memory"); __builtin_amdgcn_s_barrier(); asm volatile("" ::: "memory"); }
#define LGKM0() { asm volatile("s_waitcnt lgkmcnt(0)" ::: "memory"); __builtin_amdgcn_sched_barrier(0); }

    // prologue: stage tile 0 -> buf 0, drain
    {
#pragma unroll
        for (int q = 0; q < 4; q++) GLL(Asrc + q * 8192 + t * 16, q * 8192 + t * 16);
#pragma unroll
        for (int q = 0; q < 4; q++) GLL(Bsrc + q * 8192 + t * 16, 32768 + q * 8192 + t * 16);
        asm volatile("s_waitcnt vmcnt(0)" ::: "memory");
        BARRIER();
    }

    const int AK[12] = {0, 1, 2, 3, 0, 1, 2, 3, 4, 5, 6, 7};
    const int BK[12] = {0, 1, 2, 3, 4, 5, 6, 7, 0, 1, 2, 3};

#pragma unroll
    for (int s = 0; s < 12; s++) {
        const int buf = s & 1, nbuf = buf ^ 1;
        const char* Ab = smem + buf * 65536;
        const char* Bb = Ab + 32768;
        const int And = nbuf * 65536;
        const int Bnd = And + 32768;
        const char* aN = Asrc + (s < 11 ? AK[s + 1] : 0) * 32768;
        const char* bN = Bsrc + (s < 11 ? BK[s + 1] : 0) * 32768;

        short8v af[4], bf[4];

        // ---- phase 0: kk0, mt 0-3 (+ B kk0)
#pragma unroll
        for (int mt = 0; mt < 4; mt++) af[mt] = *(const short8v*)(Ab + aBase + mt * 2048 + c0off);
#pragma unroll
        for (int nt = 0; nt < 4; nt++) bf[nt] = *(const short8v*)(Bb + bBase + nt * 2048 + c0off);
        if (s < 11) { GLL(aN + t * 16, And + t * 16); GLL(aN + 8192 + t * 16, And + 8192 + t * 16); }
        BARRIER();
        LGKM0();
        __builtin_amdgcn_s_setprio(1);
#pragma unroll
        for (int mt = 0; mt < 4; mt++)
#pragma unroll
            for (int nt = 0; nt < 4; nt++)
                acc[mt][nt] = __builtin_amdgcn_mfma_f32_16x16x32_bf16(af[mt], bf[nt], acc[mt][nt], 0, 0, 0);
        __builtin_amdgcn_s_setprio(0);
        BARRIER();

        // ---- phase 1: kk0, mt 4-7 (B kk0 kept in bf)
#pragma unroll
        for (int mt = 0; mt < 4; mt++) af[mt] = *(const short8v*)(Ab + aBase + (mt + 4) * 2048 + c0off);
        if (s < 11) { GLL(aN + 16384 + t * 16, And + 16384 + t * 16); GLL(aN + 24576 + t * 16, And + 24576 + t * 16); }
        BARRIER();
        LGKM0();
        __builtin_amdgcn_s_setprio(1);
#pragma unroll
        for (int mt = 0; mt < 4; mt++)
#pragma unroll
            for (int nt = 0; nt < 4; nt++)
                acc[mt + 4][nt] = __builtin_amdgcn_mfma_f32_16x16x32_bf16(af[mt], bf[nt], acc[mt + 4][nt], 0, 0, 0);
        __builtin_amdgcn_s_setprio(0);
        BARRIER();

        // ---- phase 2: kk1, mt 0-3 (+ B kk1)
#pragma unroll
        for (int mt = 0; mt < 4; mt++) af[mt] = *(const short8v*)(Ab + aBase + mt * 2048 + c1off);
#pragma unroll
        for (int nt = 0; nt < 4; nt++) bf[nt] = *(const short8v*)(Bb + bBase + nt * 2048 + c1off);
        if (s < 11) { GLL(bN + t * 16, Bnd + t * 16); GLL(bN + 8192 + t * 16, Bnd + 8192 + t * 16); }
        BARRIER();
        LGKM0();
        __builtin_amdgcn_s_setprio(1);
#pragma unroll
        for (int mt = 0; mt < 4; mt++)
#pragma unroll
            for (int nt = 0; nt < 4; nt++)
                acc[mt][nt] = __builtin_amdgcn_mfma_f32_16x16x32_bf16(af[mt], bf[nt], acc[mt][nt], 0, 0, 0);
        __builtin_amdgcn_s_setprio(0);
        BARRIER();

        // ---- phase 3: kk1, mt 4-7
#pragma unroll
        for (int mt = 0; mt < 4; mt++) af[mt] = *(const short8v*)(Ab + aBase + (mt + 4) * 2048 + c1off);
        if (s < 11) { GLL(bN + 16384 + t * 16, Bnd + 16384 + t * 16); GLL(bN + 24576 + t * 16, Bnd + 24576 + t * 16); }
        BARRIER();
        LGKM0();
        __builtin_amdgcn_s_setprio(1);
#pragma unroll
        for (int mt = 0; mt < 4; mt++)
#pragma unroll
            for (int nt = 0; nt < 4; nt++)
                acc[mt + 4][nt] = __builtin_amdgcn_mfma_f32_16x16x32_bf16(af[mt], bf[nt], acc[mt + 4][nt], 0, 0, 0);
        __builtin_amdgcn_s_setprio(0);
        if (s < 11) asm volatile("s_waitcnt vmcnt(0)" ::: "memory");   // tile s+1 landed (spill-proof drain)
        BARRIER();
    }
#undef GLL

    // epilogue: per-lane argmin over nt, 16-lane reduce, cross-wn via LDS; track second-best
    float ne_v[4];
#pragma unroll
    for (int nt = 0; nt < 4; nt++) ne_v[nt] = normE[nblk * 256 + wn * 64 + nt * 16 + lr];

#pragma unroll
    for (int mt = 0; mt < 8; mt++) {
#pragma unroll
        for (int r = 0; r < 4; r++) {
            float m1 = __uint_as_float(0x7F7FFFFFu);   // FLT_MAX
            float m2 = m1;
            u32 col = 0;
#pragma unroll
            for (int nt = 0; nt < 4; nt++) {
                float f = fmaf(-2.0f, acc[mt][nt][r], ne_v[nt]);
                float mx = fmaxf(m1, f);
                m2 = fminf(m2, mx);
                bool p = f < m1;
                m1 = fminf(m1, f);
                u32 cg = (u32)(nblk * 256 + wn * 64 + nt * 16 + lr);
                col = p ? cg : col;
            }
            u64 key = ((u64)sortable(m1) << 32) | col;
#pragma unroll
            for (int off = 1; off < 16; off <<= 1) {
                u64 ko = __shfl_xor(key, off, 16);
                float m1o = __shfl_xor(m1, off, 16);
                float m2o = __shfl_xor(m2, off, 16);
                m2 = fminf(fminf(m2, m2o), fmaxf(m1, m1o));
                m1 = fminf(m1, m1o);
                key = umin64(key, ko);
            }
            if (lr == 0) {
                int slot = (wm * 128 + mt * 16 + lg * 4 + r) * 4 + wn;
                *(u64*)(smem + slot * 16) = key;
                *(float*)(smem + slot * 16 + 8) = m2;
            }
        }
    }
    __syncthreads();
    if (t < 256) {
        u64 k_i[4]; float m2_i[4];
#pragma unroll
        for (int i = 0; i < 4; i++) {
            k_i[i] = *(const u64*)(smem + (t * 4 + i) * 16);
            m2_i[i] = *(const float*)(smem + (t * 4 + i) * 16 + 8);
        }
        u64 K = umin64(umin64(k_i[0], k_i[1]), umin64(k_i[2], k_i[3]));
        float F2 = __uint_as_float(0x7F7FFFFFu);
#pragma unroll
        for (int i = 0; i < 4; i++) {
            float f1i = unsortable((u32)(k_i[i] >> 32));
            F2 = fminf(F2, (k_i[i] == K) ? m2_i[i] : f1i);
        }
        int rowg = mblk * 256 + t;
        gkey[(size_t)nblk * 32768 + rowg] = K;
        gm2[(size_t)nblk * 32768 + rowg] = F2;
    }
}

// ---- combine 4 nblk results -> idx + flag list ----
__global__ __launch_bounds__(512) void vq_combine(const u64* __restrict__ gkey, const float* __restrict__ gm2,
                                                  u32* __restrict__ idx_arr, u32* __restrict__ flaglist,
                                                  u32* __restrict__ cnt) {
    const int row = blockIdx.x * 512 + threadIdx.x;
    u64 k_i[4]; float m2_i[4];
#pragma unroll
    for (int n = 0; n < 4; n++) {
        k_i[n] = gkey[(size_t)n * 32768 + row];
        m2_i[n] = gm2[(size_t)n * 32768 + row];
    }
    u64 K = umin64(umin64(k_i[0], k_i[1]), umin64(k_i[2], k_i[3]));
    float F1 = unsortable((u32)(K >> 32));
    float F2 = __uint_as_float(0x7F7FFFFFu);
#pragma unroll
    for (int n = 0; n < 4; n++) {
        float f1i = unsortable((u32)(k_i[n] >> 32));
        F2 = fminf(F2, (k_i[n] == K) ? m2_i[n] : f1i);
    }
    idx_arr[row] = (u32)(K & 0xFFFFFFFFu);
    if (F2 - F1 < MARGIN) {
        u32 p = atomicAdd(cnt, 1u);
        flaglist[p] = (u32)row;
    }
}

// ---- exact fp32 recheck of flagged rows (bit-identical to verified round-2 math) ----
__global__ __launch_bounds__(512) void vq_recheck(const float* __restrict__ X, const float* __restrict__ E,
                                                  const float* __restrict__ normE,
                                                  const u32* __restrict__ flaglist, const u32* __restrict__ cnt,
                                                  u32* __restrict__ idx_arr) {
    __shared__ float xrow[256];
    __shared__ float r2part[32];
    __shared__ float r2s;
    __shared__ u64 wkey[8];
    const int t = threadIdx.x;
    const int n = (int)*cnt;
    for (int i = blockIdx.x; i < n; i += 256) {
        const int row = (int)flaglist[i];
        __syncthreads();
        if (t < 64) ((float4*)xrow)[t] = ((const float4*)(X + (size_t)row * 256))[t];
        __syncthreads();
        if (t < 32) {
            float s = 0.f;
#pragma unroll
            for (int k = 0; k < 8; k++) {
                float v = xrow[t * 8 + k];
                s = fmaf(v, v, s);
            }
            r2part[t] = s;
        }
        __syncthreads();
        if (t == 0) {
            float s = 0.f;
#pragma unroll
            for (int k = 0; k < 32; k++) s += r2part[k];
            r2s = s;
        }
        __syncthreads();
        const float r2 = r2s;
        const int c0 = t * 2;
        float ax = 0.f, ay = 0.f;
        for (int d = 0; d < 256; d += 4) {
#pragma unroll
            for (int dd = 0; dd < 4; dd++) {
                float xv = xrow[d + dd];
                float2 e = *(const float2*)(E + (d + dd) * NUM_EMB + c0);
                ax = fmaf(xv, e.x, ax);
                ay = fmaf(xv, e.y, ay);
            }
        }
        float2 ne = *(const float2*)(normE + c0);
        float f0 = (r2 + ne.x) - 2.0f * ax;
        float f1 = (r2 + ne.y) - 2.0f * ay;
        u64 k0 = ((u64)sortable(f0) << 32) | (u32)c0;
        u64 k1 = ((u64)sortable(f1) << 32) | (u32)(c0 + 1);
        u64 km = umin64(k0, k1);
#pragma unroll
        for (int off = 32; off; off >>= 1) km = umin64(km, __shfl_xor(km, off, 64));
        if ((t & 63) == 0) wkey[t >> 6] = km;
        __syncthreads();
        if (t == 0) {
            u64 m = wkey[0];
#pragma unroll
            for (int w2 = 1; w2 < 8; w2++) m = umin64(m, wkey[w2]);
            idx_arr[row] = (u32)(m & 0xFFFFFFFFull);
        }
    }
}

// ---- straight-through out + loss partials ----
__global__ __launch_bounds__(512) void vq_out(const float* __restrict__ X, const float* __restrict__ ET,
                                              const u32* __restrict__ idx_arr,
                                              float* __restrict__ out, float* __restrict__ partial) {
    __shared__ float lred[8];
    const int t = threadIdx.x;
    const long long base = (long long)blockIdx.x * 4096;   // 16 rows * 256
    const int dcol = t & 255, half = t >> 8;
    float lsum = 0.f;
#pragma unroll
    for (int rr = 0; rr < 8; rr++) {
        const int r = half * 8 + rr;
        const int row = blockIdx.x * 16 + r;
        const u32 idx = idx_arr[row];
        const float q = ET[(size_t)idx * EMB_DIM + dcol];
        const float x = X[base + r * EMB_DIM + dcol];
        out[base + r * EMB_DIM + dcol] = x + (q - x);
        const float df = x - q;
        lsum = fmaf(df, df, lsum);
    }
#pragma unroll
    for (int off = 32; off; off >>= 1) lsum += __shfl_down(lsum, off, 64);
    if ((t & 63) == 0) lred[t >> 6] = lsum;
    __syncthreads();
    if (t == 0) {
        float s = 0.f;
#pragma unroll
        for (int w = 0; w < 8; w++) s += lred[w];
        partial[blockIdx.x] = s;
    }
}

// ---- finish: loss = m + 0.25*m ----
__global__ void vq_finish(const float* __restrict__ partial, float* __restrict__ loss_out) {
    __shared__ float red[256];
    const int t = threadIdx.x;
    float s = 0.f;
    for (int i = t; i < 2048; i += 256) s += partial[i];
    red[t] = s;
    __syncthreads();
    for (int k = 128; k > 0; k >>= 1) {
        if (t < k) red[t] += red[t + k];
        __syncthreads();
    }
    if (t == 0) {
        const float m = red[0] / 8388608.0f;
        loss_out[0] = fmaf(0.25f, m, m);
    }
}

extern "C" void kernel_launch(void* const* d_in, const int* in_sizes, int n_in,
                              void* d_out, int out_size, void* d_ws, size_t ws_size,
                              hipStream_t stream) {
    const float* X = (const float*)d_in[0];      // (32,32,32,256) fp32
    const float* E = (const float*)d_in[1];      // (256,1024) fp32
    float* out = (float*)d_out;

    // workspace layout (bytes)
    char* ws = (char*)d_ws;
    float* ET       = (float*)(ws + 0);            // 1 MB
    float* normE    = (float*)(ws + 1048576);      // 4 KB
    float* partial  = (float*)(ws + 1052672);      // 8 KB
    char*  Es       = ws + 1060864;                // 1 MB
    u64*   gkey     = (u64*)(ws + 2109440);        // 1 MB
    float* gm2      = (float*)(ws + 3158016);      // 512 KB
    u32*   idx_arr  = (u32*)(ws + 3682304);        // 128 KB
    u32*   flaglist = (u32*)(ws + 3813376);        // 128 KB
    u32*   cnt      = (u32*)(ws + 3944448);        // 4 B

    // Xs (bf16 hi/lo, 32 MB) aliases d_out; fully consumed before vq_out overwrites.
    char* Xs = (char*)d_out;

    hipMemsetAsync(cnt, 0, 4, stream);
    vq_prep<<<354, 512, 0, stream>>>(X, E, ET, normE, Es, Xs);
    vq_gemm<<<512, 512, 131072, stream>>>(Xs, Es, normE, gkey, gm2);
    vq_combine<<<64, 512, 0, stream>>>(gkey, gm2, idx_arr, flaglist, cnt);
    vq_recheck<<<256, 512, 0, stream>>>(X, E, normE, flaglist, cnt, idx_arr);
    vq_out<<<2048, 512, 0, stream>>>(X, ET, idx_arr, out, partial);
    vq_finish<<<1, 256, 0, stream>>>(partial, out + (out_size - 1));
}